// Round 1
// baseline (60.052 us; speedup 1.0000x reference)
//
#include <hip/hip_runtime.h>

#define BB 4
#define CC 64
#define HH 128
#define WW 256

typedef unsigned int u32;

// async global->LDS, 16B per lane. LDS dest = wave-uniform base + lane*16.
__device__ __forceinline__ void gload_lds16(const float* g, float* l) {
  __builtin_amdgcn_global_load_lds(
      (const __attribute__((address_space(1))) u32*)g,
      (__attribute__((address_space(3))) u32*)l, 16, 0, 0);
}

__global__ __launch_bounds__(192) void corr_kernel(
    const float* __restrict__ first,
    const float* __restrict__ second,
    float* __restrict__ out)
{
  // second rows: [buf][9 dy rows][4 pad | 256 | 4 pad]
  __shared__ __attribute__((aligned(16))) float s_sec[2][9][264];
  __shared__ __attribute__((aligned(16))) float s_fst[2][256];

  const int tid  = threadIdx.x;
  const int lane = tid & 63;
  const int wv   = __builtin_amdgcn_readfirstlane(tid >> 6);  // 0..2, wave-uniform
  const int h    = blockIdx.x & (HH - 1);
  const int b    = blockIdx.x >> 7;
  const int l4   = lane * 4;

  // Zero both buffers once: OOB rows and the +-4 pad columns stay zero forever
  // (per-channel staging only overwrites the valid 256-float spans).
  for (int i = tid; i < 2 * 9 * 264; i += 192) (&s_sec[0][0][0])[i] = 0.0f;
  for (int i = tid; i < 2 * 256;     i += 192) (&s_fst[0][0])[i]    = 0.0f;

  float acc[3][9][4];
#pragma unroll
  for (int a = 0; a < 3; ++a)
#pragma unroll
    for (int x = 0; x < 9; ++x)
#pragma unroll
      for (int i = 0; i < 4; ++i) acc[a][x][i] = 0.0f;

  const size_t plane = (size_t)HH * WW;
  const float* fbase = first  + (size_t)b * CC * plane + (size_t)h * WW;
  const float* sbase = second + (size_t)b * CC * plane;

  auto stage = [&](int buf, int c) {
    // 9 second rows split across the 3 waves; wave 0 also stages first row.
    for (int r = wv; r < 9; r += 3) {
      const int gh = h + r - 4;
      if (0 <= gh && gh < HH) {
        gload_lds16(sbase + (size_t)c * plane + (size_t)gh * WW + l4,
                    &s_sec[buf][r][4]);
      }
    }
    if (wv == 0) {
      gload_lds16(fbase + (size_t)c * plane + l4, &s_fst[buf][0]);
    }
  };

  __syncthreads();           // zero-init visible before staging
  stage(0, 0);
  __syncthreads();           // compiler drains vmcnt before s_barrier -> buf0 ready

  for (int c = 0; c < CC; ++c) {
    const int cur = c & 1;
    if (c + 1 < CC) stage(cur ^ 1, c + 1);   // async prefetch next channel

    const float4 fq = *(const float4*)&s_fst[cur][l4];
    const float fv[4] = {fq.x, fq.y, fq.z, fq.w};

#pragma unroll
    for (int dyi = 0; dyi < 3; ++dyi) {
      const float* rp = &s_sec[cur][wv * 3 + dyi][l4];
      const float4 a0 = *(const float4*)(rp);
      const float4 a1 = *(const float4*)(rp + 4);
      const float4 a2 = *(const float4*)(rp + 8);
      const float sv[12] = {a0.x, a0.y, a0.z, a0.w,
                            a1.x, a1.y, a1.z, a1.w,
                            a2.x, a2.y, a2.z, a2.w};
#pragma unroll
      for (int dx = 0; dx < 9; ++dx)
#pragma unroll
        for (int i = 0; i < 4; ++i)
          acc[dyi][dx][i] = fmaf(fv[i], sv[i + dx], acc[dyi][dx][i]);
    }
    __syncthreads();  // staged c+1 landed; everyone done reading cur
  }

  const float sc = 1.0f / (float)CC;
#pragma unroll
  for (int dyi = 0; dyi < 3; ++dyi)
#pragma unroll
    for (int dx = 0; dx < 9; ++dx) {
      const int tc = (wv * 3 + dyi) * 9 + dx;
      float4 v = make_float4(acc[dyi][dx][0] * sc, acc[dyi][dx][1] * sc,
                             acc[dyi][dx][2] * sc, acc[dyi][dx][3] * sc);
      *(float4*)&out[(((size_t)b * 81 + tc) * HH + h) * WW + l4] = v;
    }
}

extern "C" void kernel_launch(void* const* d_in, const int* in_sizes, int n_in,
                              void* d_out, int out_size, void* d_ws, size_t ws_size,
                              hipStream_t stream) {
  const float* first  = (const float*)d_in[0];
  const float* second = (const float*)d_in[1];
  float* out = (float*)d_out;
  (void)in_sizes; (void)n_in; (void)out_size; (void)d_ws; (void)ws_size;
  corr_kernel<<<dim3(BB * HH), dim3(192), 0, stream>>>(first, second, out);
}

// Round 2
// 49.404 us; speedup vs baseline: 1.2155x; 1.2155x over previous
//
#include <hip/hip_runtime.h>

#define BB 4
#define CC 64
#define HH 128
#define WW 256

typedef unsigned int u32;

// async global->LDS, 16B per lane. LDS dest = wave-uniform base + lane*16.
__device__ __forceinline__ void gload_lds16(const float* g, float* l) {
  __builtin_amdgcn_global_load_lds(
      (const __attribute__((address_space(1))) u32*)g,
      (__attribute__((address_space(3))) u32*)l, 16, 0, 0);
}

__global__ __launch_bounds__(576) void corr_kernel(
    const float* __restrict__ first,
    const float* __restrict__ second,
    float* __restrict__ out)
{
  // 4-deep multibuffer: [buf][9 dy rows][4 pad | 256 | 4 pad]
  __shared__ __attribute__((aligned(16))) float s_sec[4][9][264];
  __shared__ __attribute__((aligned(16))) float s_fst[4][256];

  const int tid  = threadIdx.x;
  const int lane = tid & 63;
  const int wv   = __builtin_amdgcn_readfirstlane(tid >> 6);  // 0..8, wave-uniform
  // XCD-aware mapping: bid%8 ~ XCD; give each XCD a contiguous 16-row h band
  // so the 9x re-read of second rows across neighboring h hits the same L2.
  const int bid  = blockIdx.x;
  const int idx  = bid >> 3;                 // 0..63
  const int h    = (bid & 7) * 16 + (idx & 15);
  const int b    = idx >> 4;                 // 0..3
  const int l4   = lane * 4;

  // Zero all buffers once: OOB rows and +-4 pad columns stay zero forever
  // (staging only overwrites the valid 256-float spans).
  for (int i = tid; i < 4 * 9 * 264; i += 576) (&s_sec[0][0][0])[i] = 0.0f;
  for (int i = tid; i < 4 * 256;     i += 576) (&s_fst[0][0])[i]    = 0.0f;

  float acc[9][4];
#pragma unroll
  for (int x = 0; x < 9; ++x)
#pragma unroll
    for (int i = 0; i < 4; ++i) acc[x][i] = 0.0f;

  const size_t plane = (size_t)HH * WW;
  const float* fbase = first  + (size_t)b * CC * plane + (size_t)h * WW;
  const float* sbase = second + (size_t)b * CC * plane;

  const int gh = h + wv - 4;                      // this wave's second row
  const bool rowok = (0 <= gh && gh < HH);
  const int L = (rowok ? 1 : 0) + (wv == 0 ? 1 : 0);  // loads/channel, wave-uniform

  auto stage = [&](int c) {
    const int buf = c & 3;
    if (rowok)
      gload_lds16(sbase + (size_t)c * plane + (size_t)gh * WW + l4,
                  &s_sec[buf][wv][4]);
    if (wv == 0)
      gload_lds16(fbase + (size_t)c * plane + l4, &s_fst[buf][0]);
  };

  __syncthreads();          // zero-init visible before any DMA lands
  stage(0); stage(1); stage(2);   // 3 channels in flight per wave (3*L loads)

  for (int c = 0; c < CC; ++c) {
    // Wait for channel c's own loads only; keep c+1,c+2(,c+3) in flight.
    if (c < CC - 3) {
      if (L == 2)      asm volatile("s_waitcnt vmcnt(4)" ::: "memory");
      else if (L == 1) asm volatile("s_waitcnt vmcnt(2)" ::: "memory");
    } else {
      asm volatile("s_waitcnt vmcnt(0)" ::: "memory");
    }
    // All waves' c-data in LDS; all waves done computing c-1 -> safe to
    // overwrite buf[(c+3)&3] == buf[(c-1)&3] after this barrier.
    asm volatile("s_barrier" ::: "memory");

    if (c + 3 < CC) stage(c + 3);

    const int buf = c & 3;
    const float4 fq = *(const float4*)&s_fst[buf][l4];
    const float fv[4] = {fq.x, fq.y, fq.z, fq.w};

    const float* rp = &s_sec[buf][wv][l4];
    const float4 a0 = *(const float4*)(rp);
    const float4 a1 = *(const float4*)(rp + 4);
    const float4 a2 = *(const float4*)(rp + 8);
    const float sv[12] = {a0.x, a0.y, a0.z, a0.w,
                          a1.x, a1.y, a1.z, a1.w,
                          a2.x, a2.y, a2.z, a2.w};
#pragma unroll
    for (int dx = 0; dx < 9; ++dx)
#pragma unroll
      for (int i = 0; i < 4; ++i)
        acc[dx][i] = fmaf(fv[i], sv[i + dx], acc[dx][i]);
  }

  const float sc = 1.0f / (float)CC;
#pragma unroll
  for (int dx = 0; dx < 9; ++dx) {
    const int tc = wv * 9 + dx;
    float4 v = make_float4(acc[dx][0] * sc, acc[dx][1] * sc,
                           acc[dx][2] * sc, acc[dx][3] * sc);
    *(float4*)&out[(((size_t)b * 81 + tc) * HH + h) * WW + l4] = v;
  }
}

extern "C" void kernel_launch(void* const* d_in, const int* in_sizes, int n_in,
                              void* d_out, int out_size, void* d_ws, size_t ws_size,
                              hipStream_t stream) {
  const float* first  = (const float*)d_in[0];
  const float* second = (const float*)d_in[1];
  float* out = (float*)d_out;
  (void)in_sizes; (void)n_in; (void)out_size; (void)d_ws; (void)ws_size;
  corr_kernel<<<dim3(BB * HH), dim3(576), 0, stream>>>(first, second, out);
}